// Round 12
// baseline (758.121 us; speedup 1.0000x reference)
//
#include <hip/hip_runtime.h>
#include <hip/hip_bf16.h>
#include <hip/hip_fp16.h>
#include <math.h>

#define NN   20000
#define EE   160000
#define NBAT 64
#define NF   128
#define NH   64
#define NHEAD 16
#define NCLS 10
#define ETOT (EE + NN)   // edges + self loops = 180000

#define SCAN_BLK 1024
#define SCAN_NB  ((NN + SCAN_BLK - 1) / SCAN_BLK)   // 20

typedef __attribute__((ext_vector_type(8))) _Float16 half8;
typedef __attribute__((ext_vector_type(2))) _Float16 h2v;
typedef __attribute__((ext_vector_type(4))) float f32x4;
typedef unsigned short ushort_t;

#if __has_builtin(__builtin_amdgcn_fdot2)
typedef __fp16 fdot2_t __attribute__((ext_vector_type(2)));
static __device__ __forceinline__ float dot2(h2v a, h2v b, float c) {
    return __builtin_amdgcn_fdot2(__builtin_bit_cast(fdot2_t, a),
                                  __builtin_bit_cast(fdot2_t, b), c, false);
}
#else
static __device__ __forceinline__ float dot2(h2v a, h2v b, float c) {
    return c + (float)a.x * (float)b.x + (float)a.y * (float)b.y;
}
#endif

// ---------------------------------------------------------------- CSR build
// merged: edge histogram (by dst) + batch boundary detection
__global__ void k_hist_bounds(const int* __restrict__ ei, int* __restrict__ deg,
                              const int* __restrict__ batch, int* __restrict__ bstart) {
    int g = blockIdx.x * 256 + threadIdx.x;
    if (g < EE) atomicAdd(&deg[ei[EE + g]], 1);
    if (g < NN) {
        int b = batch[g];
        if (g == 0) for (int bb = 0; bb <= b; ++bb) bstart[bb] = 0;
        int bn = (g + 1 < NN) ? batch[g + 1] : NBAT;
        for (int bb = b + 1; bb <= bn; ++bb) bstart[bb] = g + 1;
    }
}

// two-level parallel scan of deg[NN]
__global__ void k_scanA(const int* __restrict__ deg, int* __restrict__ incl,
                        int* __restrict__ bsum) {
    __shared__ int sh[SCAN_BLK];
    int t = threadIdx.x, idx = blockIdx.x * SCAN_BLK + t;
    int v = (idx < NN) ? deg[idx] : 0;
    sh[t] = v;
    __syncthreads();
    for (int off = 1; off < SCAN_BLK; off <<= 1) {
        int u = (t >= off) ? sh[t - off] : 0;
        __syncthreads();
        sh[t] += u;
        __syncthreads();
    }
    incl[idx] = sh[t];
    if (t == SCAN_BLK - 1) bsum[blockIdx.x] = sh[t];
}

__global__ void k_scanB(const int* __restrict__ bsum, int* __restrict__ boff,
                        int* __restrict__ rowptr) {
    if (threadIdx.x == 0) {
        int acc = 0;
        for (int b = 0; b < SCAN_NB; ++b) { boff[b] = acc; acc += bsum[b]; }
        rowptr[NN] = acc + NN;                 // + NN self-loops
    }
}

// finalize: rowptr (self-loops folded in), self-loop at row start, cursor after
__global__ void k_scanC(const int* __restrict__ deg, const int* __restrict__ incl,
                        const int* __restrict__ boff, int* __restrict__ rowptr,
                        int* __restrict__ cursor, int* __restrict__ csr) {
    int idx = blockIdx.x * 256 + threadIdx.x;
    if (idx >= NN) return;
    int b = idx >> 10;                          // / SCAN_BLK
    int excl = boff[b] + incl[idx] - deg[idx];
    int base = excl + idx;                      // + idx self-loops before idx
    rowptr[idx] = base;
    csr[base]   = idx;                          // self-loop first
    cursor[idx] = base + 1;
}

__global__ void k_scatter(const int* __restrict__ ei, int* __restrict__ cursor,
                          int* __restrict__ csr) {
    int e = blockIdx.x * 256 + threadIdx.x;
    if (e >= EE) return;
    int s = ei[e], d = ei[EE + e];
    int pos = atomicAdd(&cursor[d], 1);
    csr[pos] = s;
}

// ---------------------------------------------------------------- weight split
// four W [K][1024] fp32 -> Wt [1024][K] fp16 (transposed); blockIdx.y selects
__global__ void k_split_w4(
    const float* __restrict__ W0, _Float16* __restrict__ T0,
    const float* __restrict__ W1, _Float16* __restrict__ T1,
    const float* __restrict__ W2, _Float16* __restrict__ T2,
    const float* __restrict__ W3, _Float16* __restrict__ T3)
{
    const int z = blockIdx.y;
    const float* W; _Float16* T; int K;
    if      (z == 0) { W = W0; T = T0; K = NF; }
    else if (z == 1) { W = W1; T = T1; K = NF; }
    else if (z == 2) { W = W2; T = T2; K = NH; }
    else             { W = W3; T = T3; K = NH; }
    int idx = blockIdx.x * 256 + threadIdx.x;
    if (idx >= K * 1024) return;
    int k = idx >> 10, n = idx & 1023;
    T[n * K + k] = (_Float16)W[idx];
}

// ------------------------------------------------- fp16 MFMA GEMM
// O[M][1024] = A[M][K] @ Wt^T + b, fp16 inputs, fp32 accum, fp16 output.
// 128x128 tile, BK=64, 4 waves. 32KB LDS reused as output tile for a
// coalesced full-line epilogue (avoids partial-line write-allocate RMW).

// layer-1: reads X fp32, converts to fp16 in-register while staging
template<int K>
__global__ __launch_bounds__(256) void k_gemm_l1(
    const float* __restrict__ X, int M,
    const _Float16* __restrict__ Wt0, const float* __restrict__ b0, _Float16* __restrict__ O0,
    const _Float16* __restrict__ Wt1, const float* __restrict__ b1, _Float16* __restrict__ O1)
{
    const _Float16* Wt = blockIdx.z ? Wt1 : Wt0;
    const float*    bi = blockIdx.z ? b1 : b0;
    _Float16*       O  = blockIdx.z ? O1 : O0;

    const int r0 = blockIdx.x * 128;
    const int c0 = blockIdx.y * 128;

    __shared__ __align__(16) ushort_t SH[128 * 128];   // 32 KB
    char* AsB = (char*)SH;             // 16 KB: A tile [128][64] fp16, swizzled
    char* WsB = (char*)SH + 16384;     // 16 KB: W tile

    const int t = threadIdx.x;
    const int lane = t & 63;
    const int wv = t >> 6, wr = wv >> 1, wc = wv & 1;
    const int fr = lane & 15;
    const int k0 = (lane >> 4) * 8;

    f32x4 acc[4][4] = {};

    for (int kt = 0; kt < K; kt += 64) {
        #pragma unroll
        for (int p = 0; p < 4; ++p) {
            int idx = p * 256 + t;       // 0..1023
            int m  = idx >> 3;           // 0..127
            int kc = (idx & 7) * 8;      // 0..56
            int gr = r0 + m;
            half8 hv = {};
            if (gr < M) {
                float4 v0 = *(const float4*)(X + (size_t)gr * K + kt + kc);
                float4 v1 = *(const float4*)(X + (size_t)gr * K + kt + kc + 4);
                hv[0] = (_Float16)v0.x; hv[1] = (_Float16)v0.y;
                hv[2] = (_Float16)v0.z; hv[3] = (_Float16)v0.w;
                hv[4] = (_Float16)v1.x; hv[5] = (_Float16)v1.y;
                hv[6] = (_Float16)v1.z; hv[7] = (_Float16)v1.w;
            }
            int sw = (m * 128 + kc * 2) ^ ((m & 7) << 4);
            *(uint4*)(AsB + sw) = __builtin_bit_cast(uint4, hv);
            uint4 wv4 = *(const uint4*)(Wt + (size_t)(c0 + m) * K + kt + kc);
            *(uint4*)(WsB + sw) = wv4;
        }
        __syncthreads();

        #pragma unroll
        for (int ks = 0; ks < 64; ks += 32) {
            half8 a[4], b[4];
            #pragma unroll
            for (int i = 0; i < 4; ++i) {
                int row = wr * 64 + i * 16 + fr;
                int off = (row * 128 + (ks + k0) * 2) ^ ((row & 7) << 4);
                a[i] = *(const half8*)(AsB + off);
            }
            #pragma unroll
            for (int j = 0; j < 4; ++j) {
                int col = wc * 64 + j * 16 + fr;
                int off = (col * 128 + (ks + k0) * 2) ^ ((col & 7) << 4);
                b[j] = *(const half8*)(WsB + off);
            }
            #pragma unroll
            for (int i = 0; i < 4; ++i)
                #pragma unroll
                for (int j = 0; j < 4; ++j)
                    acc[i][j] = __builtin_amdgcn_mfma_f32_16x16x32_f16(a[i], b[j], acc[i][j], 0, 0, 0);
        }
        __syncthreads();
    }

    // epilogue: acc+bias -> LDS (row-swizzled fp16) -> coalesced global copy
    float bj[4];
    #pragma unroll
    for (int j = 0; j < 4; ++j) bj[j] = bi[c0 + wc * 64 + j * 16 + fr];
    #pragma unroll
    for (int i = 0; i < 4; ++i) {
        #pragma unroll
        for (int r = 0; r < 4; ++r) {
            int row_l = wr * 64 + i * 16 + (lane >> 4) * 4 + r;
            int s = ((row_l >> 2) & 7) << 4;
            #pragma unroll
            for (int j = 0; j < 4; ++j) {
                int col_l = wc * 64 + j * 16 + fr;
                *(_Float16*)((char*)SH + ((row_l * 256 + col_l * 2) ^ s)) =
                    (_Float16)(acc[i][j][r] + bj[j]);
            }
        }
    }
    __syncthreads();
    #pragma unroll
    for (int it = 0; it < 8; ++it) {
        int idx = it * 256 + t;
        int row_l = idx >> 4, c16 = idx & 15;
        int gr = r0 + row_l;
        if (gr < M) {
            int s = ((row_l >> 2) & 7) << 4;
            uint4 v = *(const uint4*)((char*)SH + ((row_l * 256 + c16 * 16) ^ s));
            *(uint4*)(O + (size_t)gr * 1024 + c0 + c16 * 8) = v;
        }
    }
}

// layer-2: A already fp16 (h1 from attn layer 1), K=64 single tile
template<int K>
__global__ __launch_bounds__(256) void k_gemm_l2(
    const _Float16* __restrict__ A, int M,
    const _Float16* __restrict__ Wt0, const float* __restrict__ b0, _Float16* __restrict__ O0,
    const _Float16* __restrict__ Wt1, const float* __restrict__ b1, _Float16* __restrict__ O1)
{
    const _Float16* Wt = blockIdx.z ? Wt1 : Wt0;
    const float*    bi = blockIdx.z ? b1 : b0;
    _Float16*       O  = blockIdx.z ? O1 : O0;

    const int r0 = blockIdx.x * 128;
    const int c0 = blockIdx.y * 128;

    __shared__ __align__(16) ushort_t SH[128 * 128];   // 32 KB
    char* AsB = (char*)SH;
    char* WsB = (char*)SH + 16384;

    const int t = threadIdx.x;
    const int lane = t & 63;
    const int wv = t >> 6, wr = wv >> 1, wc = wv & 1;
    const int fr = lane & 15;
    const int k0 = (lane >> 4) * 8;

    f32x4 acc[4][4] = {};

    #pragma unroll
    for (int p = 0; p < 4; ++p) {
        int idx = p * 256 + t;
        int m  = idx >> 3;
        int kc = (idx & 7) * 8;
        int gr = r0 + m;
        uint4 av = make_uint4(0, 0, 0, 0);
        if (gr < M) av = *(const uint4*)(A + (size_t)gr * K + kc);
        int sw = (m * 128 + kc * 2) ^ ((m & 7) << 4);
        *(uint4*)(AsB + sw) = av;
        uint4 wv4 = *(const uint4*)(Wt + (size_t)(c0 + m) * K + kc);
        *(uint4*)(WsB + sw) = wv4;
    }
    __syncthreads();

    #pragma unroll
    for (int ks = 0; ks < 64; ks += 32) {
        half8 a[4], b[4];
        #pragma unroll
        for (int i = 0; i < 4; ++i) {
            int row = wr * 64 + i * 16 + fr;
            int off = (row * 128 + (ks + k0) * 2) ^ ((row & 7) << 4);
            a[i] = *(const half8*)(AsB + off);
        }
        #pragma unroll
        for (int j = 0; j < 4; ++j) {
            int col = wc * 64 + j * 16 + fr;
            int off = (col * 128 + (ks + k0) * 2) ^ ((col & 7) << 4);
            b[j] = *(const half8*)(WsB + off);
        }
        #pragma unroll
        for (int i = 0; i < 4; ++i)
            #pragma unroll
            for (int j = 0; j < 4; ++j)
                acc[i][j] = __builtin_amdgcn_mfma_f32_16x16x32_f16(a[i], b[j], acc[i][j], 0, 0, 0);
    }
    __syncthreads();

    float bj[4];
    #pragma unroll
    for (int j = 0; j < 4; ++j) bj[j] = bi[c0 + wc * 64 + j * 16 + fr];
    #pragma unroll
    for (int i = 0; i < 4; ++i) {
        #pragma unroll
        for (int r = 0; r < 4; ++r) {
            int row_l = wr * 64 + i * 16 + (lane >> 4) * 4 + r;
            int s = ((row_l >> 2) & 7) << 4;
            #pragma unroll
            for (int j = 0; j < 4; ++j) {
                int col_l = wc * 64 + j * 16 + fr;
                *(_Float16*)((char*)SH + ((row_l * 256 + col_l * 2) ^ s)) =
                    (_Float16)(acc[i][j][r] + bj[j]);
            }
        }
    }
    __syncthreads();
    #pragma unroll
    for (int it = 0; it < 8; ++it) {
        int idx = it * 256 + t;
        int row_l = idx >> 4, c16 = idx & 15;
        int gr = r0 + row_l;
        if (gr < M) {
            int s = ((row_l >> 2) & 7) << 4;
            uint4 v = *(const uint4*)((char*)SH + ((row_l * 256 + c16 * 16) ^ s));
            *(uint4*)(O + (size_t)gr * 1024 + c0 + c16 * 8) = v;
        }
    }
}

// ------------------------------------------------- attention + aggregation
// no-max softmax (logits bounded ~|2|); 4-wide predicated strips (VGPR-safe).
// SPLIT=1: write h1 fp16. SPLIT=0: fuse global_mean_pool numerator via
// atomicAdd into psums[batch[n]] (h2 never materialized).
static __device__ __forceinline__ float logit8(
    half8 a0, half8 a1, half8 xr0, half8 xr1, const h2v* att2)
{
    half8 t0 = a0 + xr0;
    half8 t1 = a1 + xr1;
    t0 = __builtin_elementwise_max(t0, t0 * (_Float16)0.2f);   // LeakyReLU(0.2)
    t1 = __builtin_elementwise_max(t1, t1 * (_Float16)0.2f);
    const h2v* p0 = (const h2v*)&t0;
    const h2v* p1 = (const h2v*)&t1;
    float lg = 0.f;
    #pragma unroll
    for (int j = 0; j < 4; ++j) lg = dot2(p0[j], att2[j], lg);
    #pragma unroll
    for (int j = 0; j < 4; ++j) lg = dot2(p1[j], att2[4 + j], lg);
    return lg;
}

template<int SPLIT>
__global__ __launch_bounds__(256) void k_attn(
    const _Float16* __restrict__ xl, const _Float16* __restrict__ xr,
    const float* __restrict__ att, const float* __restrict__ bias,
    const int* __restrict__ rowptr, const int* __restrict__ csr,
    _Float16* __restrict__ h1out, const int* __restrict__ batch,
    float* __restrict__ psums)
{
    const int wave = threadIdx.x >> 6;
    const int lane = threadIdx.x & 63;
    const int n = blockIdx.x * 4 + wave;
    if (n >= NN) return;
    const int h  = lane >> 2;
    const int cc = lane & 3;
    const int cb = h * NH + cc * 16;          // col base within [16*64]

    h2v att2[8];
    #pragma unroll
    for (int i = 0; i < 4; ++i) {
        float4 a = *(const float4*)(att + cb + i * 4);
        att2[i * 2 + 0] = h2v{(_Float16)a.x, (_Float16)a.y};
        att2[i * 2 + 1] = h2v{(_Float16)a.z, (_Float16)a.w};
    }
    const half8 xr0 = *(const half8*)(xr + (size_t)n * 1024 + cb);
    const half8 xr1 = *(const half8*)(xr + (size_t)n * 1024 + cb + 8);

    float acc[16];
    #pragma unroll
    for (int j = 0; j < 16; ++j) acc[j] = 0.f;
    float den = 0.f;

    const int e0 = rowptr[n], e1 = rowptr[n + 1];
    for (int e = e0; e < e1; e += 4) {
        int src[4];
        #pragma unroll
        for (int j = 0; j < 4; ++j) {
            int ee = e + j;
            src[j] = csr[(ee < e1) ? ee : (e1 - 1)];
        }
        half8 xa0[4], xa1[4];
        #pragma unroll
        for (int j = 0; j < 4; ++j) {
            const _Float16* p = xl + (size_t)src[j] * 1024 + cb;
            xa0[j] = *(const half8*)p;
            xa1[j] = *(const half8*)(p + 8);
        }
        #pragma unroll
        for (int j = 0; j < 4; ++j) {
            float lg = logit8(xa0[j], xa1[j], xr0, xr1, att2);
            lg += __shfl_xor(lg, 1);
            lg += __shfl_xor(lg, 2);                 // logit, replicated x4
            float p = (e + j < e1) ? __expf(lg) : 0.f;
            den += p;
            const _Float16* va = (const _Float16*)&xa0[j];
            const _Float16* vb = (const _Float16*)&xa1[j];
            #pragma unroll
            for (int q = 0; q < 8; ++q) acc[q]     = fmaf((float)va[q], p, acc[q]);
            #pragma unroll
            for (int q = 0; q < 8; ++q) acc[8 + q] = fmaf((float)vb[q], p, acc[8 + q]);
        }
    }

    const float inv = 1.f / den;
    float v[16];
    #pragma unroll
    for (int j = 0; j < 16; ++j) v[j] = acc[j] * inv;
    #pragma unroll
    for (int mask = 4; mask <= 32; mask <<= 1)
        #pragma unroll
        for (int j = 0; j < 16; ++j) v[j] += __shfl_xor(v[j], mask);

    if (h == 0) {                                    // lanes 0..3 hold head-sums
        float bvv[16];
        #pragma unroll
        for (int i = 0; i < 4; ++i)
            *(float4*)(bvv + i * 4) = *(const float4*)(bias + cc * 16 + i * 4);
        float o[16];
        #pragma unroll
        for (int j = 0; j < 16; ++j) {
            float tt = v[j] * 0.0625f + bvv[j];
            o[j] = fmaxf(tt, 0.01f * tt);            // out LeakyReLU(0.01)
        }
        if (SPLIT) {
            half8 o0, o1;
            #pragma unroll
            for (int j = 0; j < 8; ++j) { o0[j] = (_Float16)o[j]; o1[j] = (_Float16)o[8 + j]; }
            *(half8*)(h1out + (size_t)n * NH + cc * 16)     = o0;
            *(half8*)(h1out + (size_t)n * NH + cc * 16 + 8) = o1;
        } else {
            float* ps = psums + batch[n] * NH + cc * 16;
            #pragma unroll
            for (int j = 0; j < 16; ++j) atomicAdd(&ps[j], o[j]);
        }
    }
}

// ---------------------------------------------------------------- heads
__global__ void k_heads(const float* __restrict__ sums, const int* __restrict__ bstart,
                        const float* __restrict__ Wc, const float* __restrict__ bc,
                        const float* __restrict__ Wv, const float* __restrict__ bv,
                        float* __restrict__ out)
{
    const int b = blockIdx.x, c = threadIdx.x;   // 64 threads
    const float cnt = (float)(bstart[b + 1] - bstart[b]);
    const float pooled = sums[b * NH + c] / fmaxf(cnt, 1.f);
    __shared__ float pl[NH];
    pl[c] = pooled;
    __syncthreads();
    if (c < NCLS) {
        float a = bc[c];
        for (int k = 0; k < NH; ++k) a = fmaf(pl[k], Wc[k * NCLS + c], a);
        out[b * NCLS + c] = a;
    } else if (c == NCLS) {
        float a = bv[0];
        for (int k = 0; k < NH; ++k) a = fmaf(pl[k], Wv[k], a);
        out[NBAT * NCLS + b] = a;
    }
}

// ---------------------------------------------------------------- launch
extern "C" void kernel_launch(void* const* d_in, const int* in_sizes, int n_in,
                              void* d_out, int out_size, void* d_ws, size_t ws_size,
                              hipStream_t stream)
{
    const float* x     = (const float*)d_in[0];
    const int*   ei    = (const int*)  d_in[1];
    const int*   batch = (const int*)  d_in[2];
    const float* W1l = (const float*)d_in[3],  *b1l = (const float*)d_in[4];
    const float* W1r = (const float*)d_in[5],  *b1r = (const float*)d_in[6];
    const float* att1 = (const float*)d_in[7], *bias1 = (const float*)d_in[8];
    const float* W2l = (const float*)d_in[9],  *b2l = (const float*)d_in[10];
    const float* W2r = (const float*)d_in[11], *b2r = (const float*)d_in[12];
    const float* att2 = (const float*)d_in[13], *bias2 = (const float*)d_in[14];
    const float* Wc = (const float*)d_in[15],  *bc = (const float*)d_in[16];
    const float* Wv = (const float*)d_in[17],  *bv = (const float*)d_in[18];
    float* out = (float*)d_out;

    char* ws = (char*)d_ws;
    size_t off = 0;
    auto carve = [&](size_t bytes) {
        char* p = ws + off;
        off = (off + bytes + 255) & ~(size_t)255;
        return p;
    };
    _Float16* xl    = (_Float16*)carve((size_t)NN * 1024 * 2);
    _Float16* xr    = (_Float16*)carve((size_t)NN * 1024 * 2);
    float*    psums = (float*)carve((size_t)NBAT * NH * 4);
    _Float16* h1    = (_Float16*)carve((size_t)NN * NH * 2);
    _Float16* Wt1l  = (_Float16*)carve((size_t)1024 * NF * 2);
    _Float16* Wt1r  = (_Float16*)carve((size_t)1024 * NF * 2);
    _Float16* Wt2l  = (_Float16*)carve((size_t)1024 * NH * 2);
    _Float16* Wt2r  = (_Float16*)carve((size_t)1024 * NH * 2);
    int*      deg    = (int*)carve((size_t)NN * 4);
    int*      incl   = (int*)carve((size_t)SCAN_NB * SCAN_BLK * 4);
    int*      bsum   = (int*)carve((size_t)SCAN_NB * 4);
    int*      boff   = (int*)carve((size_t)SCAN_NB * 4);
    int*      cursor = (int*)carve((size_t)NN * 4);
    int*      rowptr = (int*)carve((size_t)(NN + 1) * 4);
    int*      csr    = (int*)carve((size_t)ETOT * 4);
    int*      bstart = (int*)carve((size_t)(NBAT + 1) * 4);

    // zero-init (graph-capture-safe)
    hipMemsetAsync(deg, 0, (size_t)NN * 4, stream);
    hipMemsetAsync(psums, 0, (size_t)NBAT * NH * 4, stream);

    // graph preprocessing (parallel scan)
    k_hist_bounds<<<(EE + 255) / 256, 256, 0, stream>>>(ei, deg, batch, bstart);
    k_scanA<<<SCAN_NB, SCAN_BLK, 0, stream>>>(deg, incl, bsum);
    k_scanB<<<1, 64, 0, stream>>>(bsum, boff, rowptr);
    k_scanC<<<(NN + 255) / 256, 256, 0, stream>>>(deg, incl, boff, rowptr, cursor, csr);
    k_scatter<<<(EE + 255) / 256, 256, 0, stream>>>(ei, cursor, csr);

    // weight transposes -> fp16 (one launch)
    k_split_w4<<<dim3((NF * 1024 + 255) / 256, 4), 256, 0, stream>>>(
        W1l, Wt1l, W1r, Wt1r, W2l, Wt2l, W2r, Wt2r);

    const int MB = (NN + 127) / 128;   // 157 row blocks
    // layer 1 (fp32 input, fp16 MFMA)
    k_gemm_l1<NF><<<dim3(MB, 8, 2), 256, 0, stream>>>(
        x, NN, Wt1l, b1l, xl, Wt1r, b1r, xr);
    k_attn<1><<<NN / 4, 256, 0, stream>>>(xl, xr, att1, bias1, rowptr, csr,
                                          h1, batch, psums);
    // layer 2 (fp16 input)
    k_gemm_l2<NH><<<dim3(MB, 8, 2), 256, 0, stream>>>(
        h1, NN, Wt2l, b2l, xl, Wt2r, b2r, xr);
    k_attn<0><<<NN / 4, 256, 0, stream>>>(xl, xr, att2, bias2, rowptr, csr,
                                          (_Float16*)nullptr, batch, psums);
    // heads (pool numerators already accumulated by attn<0>)
    k_heads<<<NBAT, NH, 0, stream>>>(psums, bstart, Wc, bc, Wv, bv, out);
}

// Round 13
// 328.060 us; speedup vs baseline: 2.3109x; 2.3109x over previous
//
#include <hip/hip_runtime.h>
#include <hip/hip_bf16.h>
#include <hip/hip_fp16.h>
#include <math.h>

#define NN   20000
#define EE   160000
#define NBAT 64
#define NF   128
#define NH   64
#define NHEAD 16
#define NCLS 10
#define ETOT (EE + NN)   // edges + self loops = 180000

#define SCAN_BLK 1024
#define SCAN_NB  ((NN + SCAN_BLK - 1) / SCAN_BLK)   // 20

typedef __attribute__((ext_vector_type(8))) _Float16 half8;
typedef __attribute__((ext_vector_type(2))) _Float16 h2v;
typedef __attribute__((ext_vector_type(4))) float f32x4;
typedef unsigned short ushort_t;

#if __has_builtin(__builtin_amdgcn_fdot2)
typedef __fp16 fdot2_t __attribute__((ext_vector_type(2)));
static __device__ __forceinline__ float dot2(h2v a, h2v b, float c) {
    return __builtin_amdgcn_fdot2(__builtin_bit_cast(fdot2_t, a),
                                  __builtin_bit_cast(fdot2_t, b), c, false);
}
#else
static __device__ __forceinline__ float dot2(h2v a, h2v b, float c) {
    return c + (float)a.x * (float)b.x + (float)a.y * (float)b.y;
}
#endif

// ---------------------------------------------------------------- CSR build
// merged: edge histogram (by dst) + batch boundary detection
__global__ void k_hist_bounds(const int* __restrict__ ei, int* __restrict__ deg,
                              const int* __restrict__ batch, int* __restrict__ bstart) {
    int g = blockIdx.x * 256 + threadIdx.x;
    if (g < EE) atomicAdd(&deg[ei[EE + g]], 1);
    if (g < NN) {
        int b = batch[g];
        if (g == 0) for (int bb = 0; bb <= b; ++bb) bstart[bb] = 0;
        int bn = (g + 1 < NN) ? batch[g + 1] : NBAT;
        for (int bb = b + 1; bb <= bn; ++bb) bstart[bb] = g + 1;
    }
}

// two-level parallel scan of deg[NN]
__global__ void k_scanA(const int* __restrict__ deg, int* __restrict__ incl,
                        int* __restrict__ bsum) {
    __shared__ int sh[SCAN_BLK];
    int t = threadIdx.x, idx = blockIdx.x * SCAN_BLK + t;
    int v = (idx < NN) ? deg[idx] : 0;
    sh[t] = v;
    __syncthreads();
    for (int off = 1; off < SCAN_BLK; off <<= 1) {
        int u = (t >= off) ? sh[t - off] : 0;
        __syncthreads();
        sh[t] += u;
        __syncthreads();
    }
    incl[idx] = sh[t];
    if (t == SCAN_BLK - 1) bsum[blockIdx.x] = sh[t];
}

__global__ void k_scanB(const int* __restrict__ bsum, int* __restrict__ boff,
                        int* __restrict__ rowptr) {
    if (threadIdx.x == 0) {
        int acc = 0;
        for (int b = 0; b < SCAN_NB; ++b) { boff[b] = acc; acc += bsum[b]; }
        rowptr[NN] = acc + NN;                 // + NN self-loops
    }
}

// finalize: rowptr (self-loops folded in), self-loop at row start, cursor after
__global__ void k_scanC(const int* __restrict__ deg, const int* __restrict__ incl,
                        const int* __restrict__ boff, int* __restrict__ rowptr,
                        int* __restrict__ cursor, int* __restrict__ csr) {
    int idx = blockIdx.x * 256 + threadIdx.x;
    if (idx >= NN) return;
    int b = idx >> 10;                          // / SCAN_BLK
    int excl = boff[b] + incl[idx] - deg[idx];
    int base = excl + idx;                      // + idx self-loops before idx
    rowptr[idx] = base;
    csr[base]   = idx;                          // self-loop first
    cursor[idx] = base + 1;
}

__global__ void k_scatter(const int* __restrict__ ei, int* __restrict__ cursor,
                          int* __restrict__ csr) {
    int e = blockIdx.x * 256 + threadIdx.x;
    if (e >= EE) return;
    int s = ei[e], d = ei[EE + e];
    int pos = atomicAdd(&cursor[d], 1);
    csr[pos] = s;
}

// ---------------------------------------------------------------- weight split
// four W [K][1024] fp32 -> Wt [1024][K] fp16 (transposed); blockIdx.y selects
__global__ void k_split_w4(
    const float* __restrict__ W0, _Float16* __restrict__ T0,
    const float* __restrict__ W1, _Float16* __restrict__ T1,
    const float* __restrict__ W2, _Float16* __restrict__ T2,
    const float* __restrict__ W3, _Float16* __restrict__ T3)
{
    const int z = blockIdx.y;
    const float* W; _Float16* T; int K;
    if      (z == 0) { W = W0; T = T0; K = NF; }
    else if (z == 1) { W = W1; T = T1; K = NF; }
    else if (z == 2) { W = W2; T = T2; K = NH; }
    else             { W = W3; T = T3; K = NH; }
    int idx = blockIdx.x * 256 + threadIdx.x;
    if (idx >= K * 1024) return;
    int k = idx >> 10, n = idx & 1023;
    T[n * K + k] = (_Float16)W[idx];
}

// ------------------------------------------------- fp16 MFMA GEMM
// O[M][1024] = A[M][K] @ Wt^T + b, fp16 inputs, fp32 accum, fp16 output.
// 128x128 tile, BK=64, 4 waves. 32KB LDS reused as output tile for a
// coalesced full-line epilogue (avoids partial-line write-allocate RMW).

// layer-1: reads X fp32, converts to fp16 in-register while staging
template<int K>
__global__ __launch_bounds__(256) void k_gemm_l1(
    const float* __restrict__ X, int M,
    const _Float16* __restrict__ Wt0, const float* __restrict__ b0, _Float16* __restrict__ O0,
    const _Float16* __restrict__ Wt1, const float* __restrict__ b1, _Float16* __restrict__ O1)
{
    const _Float16* Wt = blockIdx.z ? Wt1 : Wt0;
    const float*    bi = blockIdx.z ? b1 : b0;
    _Float16*       O  = blockIdx.z ? O1 : O0;

    const int r0 = blockIdx.x * 128;
    const int c0 = blockIdx.y * 128;

    __shared__ __align__(16) ushort_t SH[128 * 128];   // 32 KB
    char* AsB = (char*)SH;             // 16 KB: A tile [128][64] fp16, swizzled
    char* WsB = (char*)SH + 16384;     // 16 KB: W tile

    const int t = threadIdx.x;
    const int lane = t & 63;
    const int wv = t >> 6, wr = wv >> 1, wc = wv & 1;
    const int fr = lane & 15;
    const int k0 = (lane >> 4) * 8;

    f32x4 acc[4][4] = {};

    for (int kt = 0; kt < K; kt += 64) {
        #pragma unroll
        for (int p = 0; p < 4; ++p) {
            int idx = p * 256 + t;       // 0..1023
            int m  = idx >> 3;           // 0..127
            int kc = (idx & 7) * 8;      // 0..56
            int gr = r0 + m;
            half8 hv = {};
            if (gr < M) {
                float4 v0 = *(const float4*)(X + (size_t)gr * K + kt + kc);
                float4 v1 = *(const float4*)(X + (size_t)gr * K + kt + kc + 4);
                hv[0] = (_Float16)v0.x; hv[1] = (_Float16)v0.y;
                hv[2] = (_Float16)v0.z; hv[3] = (_Float16)v0.w;
                hv[4] = (_Float16)v1.x; hv[5] = (_Float16)v1.y;
                hv[6] = (_Float16)v1.z; hv[7] = (_Float16)v1.w;
            }
            int sw = (m * 128 + kc * 2) ^ ((m & 7) << 4);
            *(uint4*)(AsB + sw) = __builtin_bit_cast(uint4, hv);
            uint4 wv4 = *(const uint4*)(Wt + (size_t)(c0 + m) * K + kt + kc);
            *(uint4*)(WsB + sw) = wv4;
        }
        __syncthreads();

        #pragma unroll
        for (int ks = 0; ks < 64; ks += 32) {
            half8 a[4], b[4];
            #pragma unroll
            for (int i = 0; i < 4; ++i) {
                int row = wr * 64 + i * 16 + fr;
                int off = (row * 128 + (ks + k0) * 2) ^ ((row & 7) << 4);
                a[i] = *(const half8*)(AsB + off);
            }
            #pragma unroll
            for (int j = 0; j < 4; ++j) {
                int col = wc * 64 + j * 16 + fr;
                int off = (col * 128 + (ks + k0) * 2) ^ ((col & 7) << 4);
                b[j] = *(const half8*)(WsB + off);
            }
            #pragma unroll
            for (int i = 0; i < 4; ++i)
                #pragma unroll
                for (int j = 0; j < 4; ++j)
                    acc[i][j] = __builtin_amdgcn_mfma_f32_16x16x32_f16(a[i], b[j], acc[i][j], 0, 0, 0);
        }
        __syncthreads();
    }

    // epilogue: acc+bias -> LDS (row-swizzled fp16) -> coalesced global copy
    float bj[4];
    #pragma unroll
    for (int j = 0; j < 4; ++j) bj[j] = bi[c0 + wc * 64 + j * 16 + fr];
    #pragma unroll
    for (int i = 0; i < 4; ++i) {
        #pragma unroll
        for (int r = 0; r < 4; ++r) {
            int row_l = wr * 64 + i * 16 + (lane >> 4) * 4 + r;
            int s = ((row_l >> 2) & 7) << 4;
            #pragma unroll
            for (int j = 0; j < 4; ++j) {
                int col_l = wc * 64 + j * 16 + fr;
                *(_Float16*)((char*)SH + ((row_l * 256 + col_l * 2) ^ s)) =
                    (_Float16)(acc[i][j][r] + bj[j]);
            }
        }
    }
    __syncthreads();
    #pragma unroll
    for (int it = 0; it < 8; ++it) {
        int idx = it * 256 + t;
        int row_l = idx >> 4, c16 = idx & 15;
        int gr = r0 + row_l;
        if (gr < M) {
            int s = ((row_l >> 2) & 7) << 4;
            uint4 v = *(const uint4*)((char*)SH + ((row_l * 256 + c16 * 16) ^ s));
            *(uint4*)(O + (size_t)gr * 1024 + c0 + c16 * 8) = v;
        }
    }
}

// layer-2: A already fp16 (h1 from attn layer 1), K=64 single tile
template<int K>
__global__ __launch_bounds__(256) void k_gemm_l2(
    const _Float16* __restrict__ A, int M,
    const _Float16* __restrict__ Wt0, const float* __restrict__ b0, _Float16* __restrict__ O0,
    const _Float16* __restrict__ Wt1, const float* __restrict__ b1, _Float16* __restrict__ O1)
{
    const _Float16* Wt = blockIdx.z ? Wt1 : Wt0;
    const float*    bi = blockIdx.z ? b1 : b0;
    _Float16*       O  = blockIdx.z ? O1 : O0;

    const int r0 = blockIdx.x * 128;
    const int c0 = blockIdx.y * 128;

    __shared__ __align__(16) ushort_t SH[128 * 128];   // 32 KB
    char* AsB = (char*)SH;
    char* WsB = (char*)SH + 16384;

    const int t = threadIdx.x;
    const int lane = t & 63;
    const int wv = t >> 6, wr = wv >> 1, wc = wv & 1;
    const int fr = lane & 15;
    const int k0 = (lane >> 4) * 8;

    f32x4 acc[4][4] = {};

    #pragma unroll
    for (int p = 0; p < 4; ++p) {
        int idx = p * 256 + t;
        int m  = idx >> 3;
        int kc = (idx & 7) * 8;
        int gr = r0 + m;
        uint4 av = make_uint4(0, 0, 0, 0);
        if (gr < M) av = *(const uint4*)(A + (size_t)gr * K + kc);
        int sw = (m * 128 + kc * 2) ^ ((m & 7) << 4);
        *(uint4*)(AsB + sw) = av;
        uint4 wv4 = *(const uint4*)(Wt + (size_t)(c0 + m) * K + kc);
        *(uint4*)(WsB + sw) = wv4;
    }
    __syncthreads();

    #pragma unroll
    for (int ks = 0; ks < 64; ks += 32) {
        half8 a[4], b[4];
        #pragma unroll
        for (int i = 0; i < 4; ++i) {
            int row = wr * 64 + i * 16 + fr;
            int off = (row * 128 + (ks + k0) * 2) ^ ((row & 7) << 4);
            a[i] = *(const half8*)(AsB + off);
        }
        #pragma unroll
        for (int j = 0; j < 4; ++j) {
            int col = wc * 64 + j * 16 + fr;
            int off = (col * 128 + (ks + k0) * 2) ^ ((col & 7) << 4);
            b[j] = *(const half8*)(WsB + off);
        }
        #pragma unroll
        for (int i = 0; i < 4; ++i)
            #pragma unroll
            for (int j = 0; j < 4; ++j)
                acc[i][j] = __builtin_amdgcn_mfma_f32_16x16x32_f16(a[i], b[j], acc[i][j], 0, 0, 0);
    }
    __syncthreads();

    float bj[4];
    #pragma unroll
    for (int j = 0; j < 4; ++j) bj[j] = bi[c0 + wc * 64 + j * 16 + fr];
    #pragma unroll
    for (int i = 0; i < 4; ++i) {
        #pragma unroll
        for (int r = 0; r < 4; ++r) {
            int row_l = wr * 64 + i * 16 + (lane >> 4) * 4 + r;
            int s = ((row_l >> 2) & 7) << 4;
            #pragma unroll
            for (int j = 0; j < 4; ++j) {
                int col_l = wc * 64 + j * 16 + fr;
                *(_Float16*)((char*)SH + ((row_l * 256 + col_l * 2) ^ s)) =
                    (_Float16)(acc[i][j][r] + bj[j]);
            }
        }
    }
    __syncthreads();
    #pragma unroll
    for (int it = 0; it < 8; ++it) {
        int idx = it * 256 + t;
        int row_l = idx >> 4, c16 = idx & 15;
        int gr = r0 + row_l;
        if (gr < M) {
            int s = ((row_l >> 2) & 7) << 4;
            uint4 v = *(const uint4*)((char*)SH + ((row_l * 256 + c16 * 16) ^ s));
            *(uint4*)(O + (size_t)gr * 1024 + c0 + c16 * 8) = v;
        }
    }
}

// ------------------------------------------------- attention + aggregation
// no-max softmax (logits bounded ~|2|); 4-wide predicated strips (VGPR-safe).
static __device__ __forceinline__ float logit8(
    half8 a0, half8 a1, half8 xr0, half8 xr1, const h2v* att2)
{
    half8 t0 = a0 + xr0;
    half8 t1 = a1 + xr1;
    t0 = __builtin_elementwise_max(t0, t0 * (_Float16)0.2f);   // LeakyReLU(0.2)
    t1 = __builtin_elementwise_max(t1, t1 * (_Float16)0.2f);
    const h2v* p0 = (const h2v*)&t0;
    const h2v* p1 = (const h2v*)&t1;
    float lg = 0.f;
    #pragma unroll
    for (int j = 0; j < 4; ++j) lg = dot2(p0[j], att2[j], lg);
    #pragma unroll
    for (int j = 0; j < 4; ++j) lg = dot2(p1[j], att2[4 + j], lg);
    return lg;
}

template<int SPLIT>
__global__ __launch_bounds__(256) void k_attn(
    const _Float16* __restrict__ xl, const _Float16* __restrict__ xr,
    const float* __restrict__ att, const float* __restrict__ bias,
    const int* __restrict__ rowptr, const int* __restrict__ csr,
    float* __restrict__ hout, _Float16* __restrict__ h1out)
{
    const int wave = threadIdx.x >> 6;
    const int lane = threadIdx.x & 63;
    const int n = blockIdx.x * 4 + wave;
    if (n >= NN) return;
    const int h  = lane >> 2;
    const int cc = lane & 3;
    const int cb = h * NH + cc * 16;          // col base within [16*64]

    h2v att2[8];
    #pragma unroll
    for (int i = 0; i < 4; ++i) {
        float4 a = *(const float4*)(att + cb + i * 4);
        att2[i * 2 + 0] = h2v{(_Float16)a.x, (_Float16)a.y};
        att2[i * 2 + 1] = h2v{(_Float16)a.z, (_Float16)a.w};
    }
    const half8 xr0 = *(const half8*)(xr + (size_t)n * 1024 + cb);
    const half8 xr1 = *(const half8*)(xr + (size_t)n * 1024 + cb + 8);

    float acc[16];
    #pragma unroll
    for (int j = 0; j < 16; ++j) acc[j] = 0.f;
    float den = 0.f;

    const int e0 = rowptr[n], e1 = rowptr[n + 1];
    for (int e = e0; e < e1; e += 4) {
        int src[4];
        #pragma unroll
        for (int j = 0; j < 4; ++j) {
            int ee = e + j;
            src[j] = csr[(ee < e1) ? ee : (e1 - 1)];
        }
        half8 xa0[4], xa1[4];
        #pragma unroll
        for (int j = 0; j < 4; ++j) {
            const _Float16* p = xl + (size_t)src[j] * 1024 + cb;
            xa0[j] = *(const half8*)p;
            xa1[j] = *(const half8*)(p + 8);
        }
        #pragma unroll
        for (int j = 0; j < 4; ++j) {
            float lg = logit8(xa0[j], xa1[j], xr0, xr1, att2);
            lg += __shfl_xor(lg, 1);
            lg += __shfl_xor(lg, 2);                 // logit, replicated x4
            float p = (e + j < e1) ? __expf(lg) : 0.f;
            den += p;
            const _Float16* va = (const _Float16*)&xa0[j];
            const _Float16* vb = (const _Float16*)&xa1[j];
            #pragma unroll
            for (int q = 0; q < 8; ++q) acc[q]     = fmaf((float)va[q], p, acc[q]);
            #pragma unroll
            for (int q = 0; q < 8; ++q) acc[8 + q] = fmaf((float)vb[q], p, acc[8 + q]);
        }
    }

    const float inv = 1.f / den;
    float v[16];
    #pragma unroll
    for (int j = 0; j < 16; ++j) v[j] = acc[j] * inv;
    #pragma unroll
    for (int mask = 4; mask <= 32; mask <<= 1)
        #pragma unroll
        for (int j = 0; j < 16; ++j) v[j] += __shfl_xor(v[j], mask);

    if (h == 0) {                                    // lanes 0..3 hold head-sums
        float bvv[16];
        #pragma unroll
        for (int i = 0; i < 4; ++i)
            *(float4*)(bvv + i * 4) = *(const float4*)(bias + cc * 16 + i * 4);
        float o[16];
        #pragma unroll
        for (int j = 0; j < 16; ++j) {
            float tt = v[j] * 0.0625f + bvv[j];
            o[j] = fmaxf(tt, 0.01f * tt);            // out LeakyReLU(0.01)
        }
        if (SPLIT) {
            half8 o0, o1;
            #pragma unroll
            for (int j = 0; j < 8; ++j) { o0[j] = (_Float16)o[j]; o1[j] = (_Float16)o[8 + j]; }
            *(half8*)(h1out + (size_t)n * NH + cc * 16)     = o0;
            *(half8*)(h1out + (size_t)n * NH + cc * 16 + 8) = o1;
        } else {
            #pragma unroll
            for (int i = 0; i < 4; ++i)
                *(float4*)(hout + (size_t)n * NH + cc * 16 + i * 4) =
                    make_float4(o[i * 4], o[i * 4 + 1], o[i * 4 + 2], o[i * 4 + 3]);
        }
    }
}

// ---------------------------------------------------------------- pooling
// contention-free: 157 blocks, run-length accumulate over sorted batch ids,
// <=2 atomics per thread (round-12's fused 1.28M-atomic version was 10x slower)
#define PNODES 128
__global__ __launch_bounds__(256) void k_pool_partial(
    const float* __restrict__ h2buf, const int* __restrict__ batch,
    float* __restrict__ sums)
{
    const int n0 = blockIdx.x * PNODES;
    const int c = threadIdx.x & 63;
    const int r = threadIdx.x >> 6;          // 0..3
    const int nend = (n0 + PNODES < NN) ? n0 + PNODES : NN;
    float s = 0.f;
    int bcur = -1;
    for (int n = n0 + r; n < nend; n += 4) {
        int b = batch[n];                     // wave-uniform -> broadcast
        if (b != bcur) {
            if (bcur >= 0) atomicAdd(&sums[bcur * NH + c], s);
            bcur = b; s = 0.f;
        }
        s += h2buf[(size_t)n * NH + c];
    }
    if (bcur >= 0) atomicAdd(&sums[bcur * NH + c], s);
}

__global__ void k_heads(const float* __restrict__ sums, const int* __restrict__ bstart,
                        const float* __restrict__ Wc, const float* __restrict__ bc,
                        const float* __restrict__ Wv, const float* __restrict__ bv,
                        float* __restrict__ out)
{
    const int b = blockIdx.x, c = threadIdx.x;   // 64 threads
    const float cnt = (float)(bstart[b + 1] - bstart[b]);
    const float pooled = sums[b * NH + c] / fmaxf(cnt, 1.f);
    __shared__ float pl[NH];
    pl[c] = pooled;
    __syncthreads();
    if (c < NCLS) {
        float a = bc[c];
        for (int k = 0; k < NH; ++k) a = fmaf(pl[k], Wc[k * NCLS + c], a);
        out[b * NCLS + c] = a;
    } else if (c == NCLS) {
        float a = bv[0];
        for (int k = 0; k < NH; ++k) a = fmaf(pl[k], Wv[k], a);
        out[NBAT * NCLS + b] = a;
    }
}

// ---------------------------------------------------------------- launch
extern "C" void kernel_launch(void* const* d_in, const int* in_sizes, int n_in,
                              void* d_out, int out_size, void* d_ws, size_t ws_size,
                              hipStream_t stream)
{
    const float* x     = (const float*)d_in[0];
    const int*   ei    = (const int*)  d_in[1];
    const int*   batch = (const int*)  d_in[2];
    const float* W1l = (const float*)d_in[3],  *b1l = (const float*)d_in[4];
    const float* W1r = (const float*)d_in[5],  *b1r = (const float*)d_in[6];
    const float* att1 = (const float*)d_in[7], *bias1 = (const float*)d_in[8];
    const float* W2l = (const float*)d_in[9],  *b2l = (const float*)d_in[10];
    const float* W2r = (const float*)d_in[11], *b2r = (const float*)d_in[12];
    const float* att2 = (const float*)d_in[13], *bias2 = (const float*)d_in[14];
    const float* Wc = (const float*)d_in[15],  *bc = (const float*)d_in[16];
    const float* Wv = (const float*)d_in[17],  *bv = (const float*)d_in[18];
    float* out = (float*)d_out;

    char* ws = (char*)d_ws;
    size_t off = 0;
    auto carve = [&](size_t bytes) {
        char* p = ws + off;
        off = (off + bytes + 255) & ~(size_t)255;
        return p;
    };
    _Float16* xl    = (_Float16*)carve((size_t)NN * 1024 * 2);
    _Float16* xr    = (_Float16*)carve((size_t)NN * 1024 * 2);
    float*    h2b   = (float*)carve((size_t)NN * NH * 4);
    float*    psums = (float*)carve((size_t)NBAT * NH * 4);
    _Float16* h1    = (_Float16*)carve((size_t)NN * NH * 2);
    _Float16* Wt1l  = (_Float16*)carve((size_t)1024 * NF * 2);
    _Float16* Wt1r  = (_Float16*)carve((size_t)1024 * NF * 2);
    _Float16* Wt2l  = (_Float16*)carve((size_t)1024 * NH * 2);
    _Float16* Wt2r  = (_Float16*)carve((size_t)1024 * NH * 2);
    int*      deg    = (int*)carve((size_t)NN * 4);
    int*      incl   = (int*)carve((size_t)SCAN_NB * SCAN_BLK * 4);
    int*      bsum   = (int*)carve((size_t)SCAN_NB * 4);
    int*      boff   = (int*)carve((size_t)SCAN_NB * 4);
    int*      cursor = (int*)carve((size_t)NN * 4);
    int*      rowptr = (int*)carve((size_t)(NN + 1) * 4);
    int*      csr    = (int*)carve((size_t)ETOT * 4);
    int*      bstart = (int*)carve((size_t)(NBAT + 1) * 4);

    // zero-init (graph-capture-safe)
    hipMemsetAsync(deg, 0, (size_t)NN * 4, stream);
    hipMemsetAsync(psums, 0, (size_t)NBAT * NH * 4, stream);

    // graph preprocessing (parallel scan)
    k_hist_bounds<<<(EE + 255) / 256, 256, 0, stream>>>(ei, deg, batch, bstart);
    k_scanA<<<SCAN_NB, SCAN_BLK, 0, stream>>>(deg, incl, bsum);
    k_scanB<<<1, 64, 0, stream>>>(bsum, boff, rowptr);
    k_scanC<<<(NN + 255) / 256, 256, 0, stream>>>(deg, incl, boff, rowptr, cursor, csr);
    k_scatter<<<(EE + 255) / 256, 256, 0, stream>>>(ei, cursor, csr);

    // weight transposes -> fp16 (one launch)
    k_split_w4<<<dim3((NF * 1024 + 255) / 256, 4), 256, 0, stream>>>(
        W1l, Wt1l, W1r, Wt1r, W2l, Wt2l, W2r, Wt2r);

    const int MB = (NN + 127) / 128;   // 157 row blocks
    // layer 1 (fp32 input, fp16 MFMA)
    k_gemm_l1<NF><<<dim3(MB, 8, 2), 256, 0, stream>>>(
        x, NN, Wt1l, b1l, xl, Wt1r, b1r, xr);
    k_attn<1><<<NN / 4, 256, 0, stream>>>(xl, xr, att1, bias1, rowptr, csr,
                                          (float*)nullptr, h1);
    // layer 2 (fp16 input)
    k_gemm_l2<NH><<<dim3(MB, 8, 2), 256, 0, stream>>>(
        h1, NN, Wt2l, b2l, xl, Wt2r, b2r, xr);
    k_attn<0><<<NN / 4, 256, 0, stream>>>(xl, xr, att2, bias2, rowptr, csr,
                                          h2b, (_Float16*)nullptr);
    // pool + heads (two-stage, contention-free)
    k_pool_partial<<<(NN + PNODES - 1) / PNODES, 256, 0, stream>>>(h2b, batch, psums);
    k_heads<<<NBAT, NH, 0, stream>>>(psums, bstart, Wc, bc, Wv, bv, out);
}